// Round 1
// baseline (915.091 us; speedup 1.0000x reference)
//
#include <hip/hip_runtime.h>
#include <math.h>

#define T_ 128
#define B_ 64
#define H_ 512
#define E_ 256
#define V_ 32000
#define VT_ (V_ + T_)   // 32128
#define UNK_ 2
#define EPS_ 1e-10f

// ---------------- zero helper (atomic targets) ----------------
__global__ void zero_k(float* __restrict__ p, int n) {
    int i = blockIdx.x * 256 + threadIdx.x;
    if (i < n) p[i] = 0.f;
}

// ---------------- generic batched matvec ----------------------
// out[b,m] = bias[m] + sum_k W[m*ldw+k] * x[b*K+k]
__global__ void matvec_k(const float* __restrict__ W, int ldw,
                         const float* __restrict__ x,
                         const float* __restrict__ bias,
                         float* __restrict__ out, int M, int K) {
    int wid  = blockIdx.x * 4 + (threadIdx.x >> 6);
    int lane = threadIdx.x & 63;
    int b = wid / M, m = wid % M;
    if (b >= B_) return;
    const float* wr = W + (size_t)m * ldw;
    const float* xr = x + (size_t)b * K;
    float s = 0.f;
    for (int k = lane; k < K; k += 64) s += wr[k] * xr[k];
    #pragma unroll
    for (int off = 32; off > 0; off >>= 1) s += __shfl_down(s, off);
    if (lane == 0) out[b * M + m] = s + bias[m];
}

// gi matvec with gathered x = [emb[z[b]] (E), ctx[b] (H)]
__global__ void gi_matvec_k(const float* __restrict__ Wih,  // (1536, 768)
                            const float* __restrict__ emb,
                            const int* __restrict__ z,
                            const float* __restrict__ ctx,
                            const float* __restrict__ bih,
                            float* __restrict__ gi) {
    const int M = 1536, K = 768;
    int wid  = blockIdx.x * 4 + (threadIdx.x >> 6);
    int lane = threadIdx.x & 63;
    int b = wid / M, m = wid % M;
    if (b >= B_) return;
    const float* wr = Wih + (size_t)m * K;
    const float* er = emb + (size_t)z[b] * E_;
    const float* cr = ctx + (size_t)b * H_;
    float s = 0.f;
    for (int k = lane; k < K; k += 64) {
        float xv = (k < E_) ? er[k] : cr[k - E_];
        s += wr[k] * xv;
    }
    #pragma unroll
    for (int off = 32; off > 0; off >>= 1) s += __shfl_down(s, off);
    if (lane == 0) gi[b * M + m] = s + bih[m];
}

// ------- enc GEMM (8192x512 @ 512x512^T) with tanh+dot epilogue -------
// out[row=b*T+t] += sum_col dotv[col] * tanh( (enc_row . W[col]) + addv[col] )
#define BK 32
__global__ void enc_gemm_dot_k(const float* __restrict__ enc,  // (T,B,H)
                               const float* __restrict__ W, int ldw,
                               const float* __restrict__ addv, int add_per_b,
                               const float* __restrict__ dotv, int dot_per_b,
                               float* __restrict__ out) {      // (B*T), zeroed
    __shared__ float As[64][BK + 1];
    __shared__ float Bs[64][BK + 1];
    __shared__ float red[64];
    int r0 = blockIdx.x * 64;            // global row (b*T + t)
    int c0 = blockIdx.y * 64;
    int tid = threadIdx.x;
    int b  = r0 / T_;
    int t0 = r0 % T_;
    int tx = tid & 15, ty = tid >> 4;
    float acc[4][4] = {};
    for (int k0 = 0; k0 < H_; k0 += BK) {
        for (int l = tid; l < 64 * BK; l += 256) {
            int row = l / BK, k = l % BK;
            As[row][k] = enc[((size_t)(t0 + row) * B_ + b) * H_ + k0 + k];
            Bs[row][k] = W[(size_t)(c0 + row) * ldw + k0 + k];
        }
        __syncthreads();
        #pragma unroll
        for (int kk = 0; kk < BK; ++kk) {
            float a[4], bb[4];
            #pragma unroll
            for (int i = 0; i < 4; i++) a[i] = As[ty * 4 + i][kk];
            #pragma unroll
            for (int j = 0; j < 4; j++) bb[j] = Bs[tx * 4 + j][kk];
            #pragma unroll
            for (int i = 0; i < 4; i++)
                #pragma unroll
                for (int j = 0; j < 4; j++) acc[i][j] += a[i] * bb[j];
        }
        __syncthreads();
    }
    if (tid < 64) red[tid] = 0.f;
    __syncthreads();
    #pragma unroll
    for (int i = 0; i < 4; i++) {
        float rs = 0.f;
        #pragma unroll
        for (int j = 0; j < 4; j++) {
            int col = c0 + tx * 4 + j;
            float addt = add_per_b ? addv[b * H_ + col] : addv[col];
            float e = tanhf(acc[i][j] + addt);
            float d = dot_per_b ? dotv[b * H_ + col] : dotv[col];
            rs += d * e;
        }
        atomicAdd(&red[ty * 4 + i], rs);
    }
    __syncthreads();
    if (tid < 64) atomicAdd(&out[r0 + tid], red[tid]);
}

// ---------------- alpha = softmax over T per b ----------------
__global__ void softmax_t_k(const float* __restrict__ score, float* __restrict__ alpha) {
    __shared__ float red[T_];
    int b = blockIdx.x, t = threadIdx.x;
    float v = score[b * T_ + t];
    red[t] = v; __syncthreads();
    for (int s = 64; s > 0; s >>= 1) { if (t < s) red[t] = fmaxf(red[t], red[t + s]); __syncthreads(); }
    float m = red[0]; __syncthreads();
    float e = expf(v - m);
    red[t] = e; __syncthreads();
    for (int s = 64; s > 0; s >>= 1) { if (t < s) red[t] += red[t + s]; __syncthreads(); }
    alpha[b * T_ + t] = e / red[0];
}

// ---------------- ctx = alpha-weighted sum over enc ----------------
__global__ void ctx_k(const float* __restrict__ enc, const float* __restrict__ alpha,
                      float* __restrict__ ctx, float* __restrict__ xcat) {
    __shared__ float al[T_];
    int b = blockIdx.x;
    int h = blockIdx.y * 256 + threadIdx.x;
    if (threadIdx.x < T_) al[threadIdx.x] = alpha[b * T_ + threadIdx.x];
    __syncthreads();
    float s = 0.f;
    for (int t = 0; t < T_; ++t) s += al[t] * enc[((size_t)t * B_ + b) * H_ + h];
    ctx[b * H_ + h] = s;
    xcat[b * 1024 + 512 + h] = s;
}

// ---------------- GRU elementwise ----------------
__global__ void gru_k(const float* __restrict__ gi, const float* __restrict__ gh,
                      const float* __restrict__ hprev,
                      float* __restrict__ out, float* __restrict__ hnew,
                      float* __restrict__ xcat) {
    int b = blockIdx.x;
    int m = blockIdx.y * 256 + threadIdx.x;
    float ir = gi[b * 1536 + m],        hr = gh[b * 1536 + m];
    float iz = gi[b * 1536 + 512 + m],  hz = gh[b * 1536 + 512 + m];
    float in_ = gi[b * 1536 + 1024 + m], hn = gh[b * 1536 + 1024 + m];
    float r = 1.f / (1.f + expf(-(ir + hr)));
    float z = 1.f / (1.f + expf(-(iz + hz)));
    float n = tanhf(in_ + r * hn);
    float h = hprev[b * 512 + m];
    float hv = (1.f - z) * n + z * h;
    out[b * 512 + m] = hv;                 // gru_out
    out[B_ * 512 + b * 512 + m] = hv;      // new_hidden
    hnew[b * 512 + m] = hv;
    xcat[b * 1024 + m] = hv;
}

// ---------------- gen_score GEMM: (64,1024) x (V,1024)^T ----------------
__global__ void proj_gemm_k(const float* __restrict__ xcat,
                            const float* __restrict__ Wp,
                            const float* __restrict__ bp,
                            float* __restrict__ gen) {
    __shared__ float As[64][33];
    __shared__ float Bs[64][33];
    int c0 = blockIdx.x * 64;
    int tid = threadIdx.x;
    int tx = tid & 15, ty = tid >> 4;
    float acc[4][4] = {};
    for (int k0 = 0; k0 < 1024; k0 += 32) {
        for (int l = tid; l < 64 * 32; l += 256) {
            int row = l >> 5, k = l & 31;
            As[row][k] = xcat[row * 1024 + k0 + k];
            Bs[row][k] = Wp[(size_t)(c0 + row) * 1024 + k0 + k];
        }
        __syncthreads();
        #pragma unroll
        for (int kk = 0; kk < 32; ++kk) {
            float a[4], bb[4];
            #pragma unroll
            for (int i = 0; i < 4; i++) a[i] = As[ty * 4 + i][kk];
            #pragma unroll
            for (int j = 0; j < 4; j++) bb[j] = Bs[tx * 4 + j][kk];
            #pragma unroll
            for (int i = 0; i < 4; i++)
                #pragma unroll
                for (int j = 0; j < 4; j++) acc[i][j] += a[i] * bb[j];
        }
        __syncthreads();
    }
    #pragma unroll
    for (int i = 0; i < 4; i++)
        #pragma unroll
        for (int j = 0; j < 4; j++) {
            int b = ty * 4 + i, v = c0 + tx * 4 + j;
            gen[(size_t)b * V_ + v] = acc[i][j] + bp[v];
        }
}

// ---------------- raw stats: cmax, ex, total ----------------
__global__ void raw_stats_k(float* __restrict__ raw, float* __restrict__ cmax,
                            float* __restrict__ total) {
    __shared__ float red[T_];
    int b = blockIdx.x, t = threadIdx.x;
    float v = raw[b * T_ + t];
    red[t] = v; __syncthreads();
    for (int s = 64; s > 0; s >>= 1) { if (t < s) red[t] = fmaxf(red[t], red[t + s]); __syncthreads(); }
    float m = red[0]; __syncthreads();
    float e = expf(v - m);
    red[t] = e; __syncthreads();
    for (int s = 64; s > 0; s >>= 1) { if (t < s) red[t] += red[t + s]; __syncthreads(); }
    if (t == 0) { cmax[b] = m; total[b] = red[0]; }
    raw[b * T_ + t] = e;   // overwrite with exp
}

// ---------------- scatter ex into scat ----------------
__global__ void scatter_k(const float* __restrict__ ex, const int* __restrict__ u_input,
                          float* __restrict__ scat) {
    int b = blockIdx.x, t = threadIdx.x;
    int id = u_input[t * B_ + b];
    if (id != 0) {
        int j = (id == UNK_) ? (V_ + t) : id;
        atomicAdd(&scat[(size_t)b * VT_ + j], ex[b * T_ + t]);
    }
}

// ---------------- final: concat softmax + proba ----------------
__global__ void final_k(const float* __restrict__ gen, const float* __restrict__ scat,
                        const float* __restrict__ cmax, const float* __restrict__ total,
                        float* __restrict__ proba) {
    __shared__ float rmax[256], rsum[256], rgmax[256];
    __shared__ float sh[4];
    int b = blockIdx.x, tid = threadIdx.x;
    const float* sr = scat + (size_t)b * VT_;
    const float* gr = gen + (size_t)b * V_;
    float smax = 0.f, ssum = 0.f, gmax = -1e30f;
    for (int j = tid; j < VT_; j += 256) {
        float s = sr[j];
        smax = fmaxf(smax, s); ssum += s;
        if (j < V_) gmax = fmaxf(gmax, gr[j]);
    }
    rmax[tid] = smax; rsum[tid] = ssum; rgmax[tid] = gmax; __syncthreads();
    for (int s = 128; s > 0; s >>= 1) {
        if (tid < s) {
            rmax[tid] = fmaxf(rmax[tid], rmax[tid + s]);
            rsum[tid] += rsum[tid + s];
            rgmax[tid] = fmaxf(rgmax[tid], rgmax[tid + s]);
        }
        __syncthreads();
    }
    float cm = cmax[b], tot = total[b];
    if (tid == 0) {
        float umax = cm + logf(EPS_ * tot + (1.f - EPS_) * rmax[0]);
        sh[0] = fmaxf(rgmax[0], umax);
        sh[3] = rsum[0];
    }
    __syncthreads();
    float M = sh[0];
    float zg = 0.f;
    for (int j = tid; j < V_; j += 256) zg += expf(gr[j] - M);
    rsum[tid] = zg; __syncthreads();
    for (int s = 128; s > 0; s >>= 1) { if (tid < s) rsum[tid] += rsum[tid + s]; __syncthreads(); }
    if (tid == 0) {
        float coef = expf(cm - M);
        float Z = rsum[0] + coef * (EPS_ * tot * (float)VT_ + (1.f - EPS_) * sh[3]);
        sh[1] = 1.f / Z;
        sh[2] = coef;
    }
    __syncthreads();
    float invZ = sh[1], coef = sh[2];
    float* pr = proba + (size_t)b * VT_;
    for (int j = tid; j < VT_; j += 256) {
        float c = coef * (EPS_ * tot + (1.f - EPS_) * sr[j]) * invZ;
        float p = c + ((j < V_) ? expf(gr[j] - M) * invZ : 0.f);
        pr[j] = p;
    }
}

extern "C" void kernel_launch(void* const* d_in, const int* in_sizes, int n_in,
                              void* d_out, int out_size, void* d_ws, size_t ws_size,
                              hipStream_t stream) {
    const float* u_enc   = (const float*)d_in[0];
    const int*   z_tm1   = (const int*)d_in[1];
    const float* last_h  = (const float*)d_in[2];
    const int*   u_input = (const int*)d_in[3];
    const float* emb     = (const float*)d_in[4];
    const float* attn_W  = (const float*)d_in[5];
    const float* attn_b  = (const float*)d_in[6];
    const float* attn_v  = (const float*)d_in[7];
    const float* gru_Wih = (const float*)d_in[8];
    const float* gru_Whh = (const float*)d_in[9];
    const float* gru_bih = (const float*)d_in[10];
    const float* gru_bhh = (const float*)d_in[11];
    const float* proj_W  = (const float*)d_in[12];
    const float* proj_b  = (const float*)d_in[13];
    const float* copy1_W = (const float*)d_in[14];
    const float* copy1_b = (const float*)d_in[15];
    float* out = (float*)d_out;

    float* ws    = (float*)d_ws;
    // atomic targets contiguous at the front, zeroed with one kernel
    float* score = ws;                          // B*T
    float* rawb  = score + B_ * T_;             // B*T
    float* scat  = rawb + B_ * T_;              // B*VT
    float* Wh    = scat + (size_t)B_ * VT_;     // B*H
    float* gh    = Wh + B_ * H_;                // B*1536
    float* alpha = gh + B_ * 1536;              // B*T
    float* ctx   = alpha + B_ * T_;             // B*H
    float* gi    = ctx + B_ * H_;               // B*1536
    float* hnew  = gi + B_ * 1536;              // B*H
    float* xcat  = hnew + B_ * H_;              // B*1024
    float* gen   = xcat + B_ * 1024;            // B*V
    float* cmaxb = gen + (size_t)B_ * V_;       // B
    float* totalb= cmaxb + B_;                  // B

    int nzero = B_ * T_ * 2 + B_ * VT_;
    zero_k<<<(nzero + 255) / 256, 256, 0, stream>>>(ws, nzero);

    // Wh = attn_W[:, :H] @ h + attn_b ; gh = gru_Whh @ h + gru_bhh
    matvec_k<<<B_ * H_ / 4, 256, 0, stream>>>(attn_W, 2 * H_, last_h, attn_b, Wh, H_, H_);
    matvec_k<<<B_ * 1536 / 4, 256, 0, stream>>>(gru_Whh, H_, last_h, gru_bhh, gh, 1536, H_);

    dim3 g2(T_ * B_ / 64, H_ / 64);
    // attn scores: score[b,t] = sum_hh attn_v[hh]*tanh(Wh[b,hh] + enc.attn_W2)
    enc_gemm_dot_k<<<g2, 256, 0, stream>>>(u_enc, attn_W + H_, 2 * H_, Wh, 1, attn_v, 0, score);
    softmax_t_k<<<B_, T_, 0, stream>>>(score, alpha);
    ctx_k<<<dim3(B_, 2), 256, 0, stream>>>(u_enc, alpha, ctx, xcat);

    gi_matvec_k<<<B_ * 1536 / 4, 256, 0, stream>>>(gru_Wih, emb, z_tm1, ctx, gru_bih, gi);
    gru_k<<<dim3(B_, 2), 256, 0, stream>>>(gi, gh, last_h, out, hnew, xcat);

    proj_gemm_k<<<V_ / 64, 256, 0, stream>>>(xcat, proj_W, proj_b, gen);

    // copy raw: raw[b,t] = sum_i hnew[b,i]*tanh(copy1_b[i] + enc.copy1_W)
    enc_gemm_dot_k<<<g2, 256, 0, stream>>>(u_enc, copy1_W, H_, copy1_b, 0, hnew, 1, rawb);

    raw_stats_k<<<B_, T_, 0, stream>>>(rawb, cmaxb, totalb);
    scatter_k<<<B_, T_, 0, stream>>>(rawb, u_input, scat);
    final_k<<<B_, 256, 0, stream>>>(gen, scat, cmaxb, totalb, out + 2 * B_ * H_);
}

// Round 2
// 700.817 us; speedup vs baseline: 1.3057x; 1.3057x over previous
//
#include <hip/hip_runtime.h>
#include <math.h>

#define T_ 128
#define B_ 64
#define H_ 512
#define E_ 256
#define V_ 32000
#define VT_ (V_ + T_)   // 32128
#define UNK_ 2
#define EPS_ 1e-10f

typedef __attribute__((ext_vector_type(8))) __bf16 bf16x8;
typedef __attribute__((ext_vector_type(4))) float floatx4;

// ---------------- zero helper (atomic targets) ----------------
__global__ void zero_k(float* __restrict__ p, int n) {
    int i = blockIdx.x * 256 + threadIdx.x;
    if (i < n) p[i] = 0.f;
}

// ---------------- generic batched matvec ----------------------
// out[b,m] = bias[m] + sum_k W[m*ldw+k] * x[b*K+k]
__global__ void matvec_k(const float* __restrict__ W, int ldw,
                         const float* __restrict__ x,
                         const float* __restrict__ bias,
                         float* __restrict__ out, int M, int K) {
    int wid  = blockIdx.x * 4 + (threadIdx.x >> 6);
    int lane = threadIdx.x & 63;
    int b = wid / M, m = wid % M;
    if (b >= B_) return;
    const float* wr = W + (size_t)m * ldw;
    const float* xr = x + (size_t)b * K;
    float s = 0.f;
    for (int k = lane; k < K; k += 64) s += wr[k] * xr[k];
    #pragma unroll
    for (int off = 32; off > 0; off >>= 1) s += __shfl_down(s, off);
    if (lane == 0) out[b * M + m] = s + bias[m];
}

// gi matvec with gathered x = [emb[z[b]] (E), ctx[b] (H)]
__global__ void gi_matvec_k(const float* __restrict__ Wih,  // (1536, 768)
                            const float* __restrict__ emb,
                            const int* __restrict__ z,
                            const float* __restrict__ ctx,
                            const float* __restrict__ bih,
                            float* __restrict__ gi) {
    const int M = 1536, K = 768;
    int wid  = blockIdx.x * 4 + (threadIdx.x >> 6);
    int lane = threadIdx.x & 63;
    int b = wid / M, m = wid % M;
    if (b >= B_) return;
    const float* wr = Wih + (size_t)m * K;
    const float* er = emb + (size_t)z[b] * E_;
    const float* cr = ctx + (size_t)b * H_;
    float s = 0.f;
    for (int k = lane; k < K; k += 64) {
        float xv = (k < E_) ? er[k] : cr[k - E_];
        s += wr[k] * xv;
    }
    #pragma unroll
    for (int off = 32; off > 0; off >>= 1) s += __shfl_down(s, off);
    if (lane == 0) gi[b * M + m] = s + bih[m];
}

// ------- enc GEMM (8192x512 @ 512x512^T) with tanh+dot epilogue -------
// out[row=b*T+t] += sum_col dotv[col] * tanh( (enc_row . W[col]) + addv[col] )
#define BK 32
__global__ void enc_gemm_dot_k(const float* __restrict__ enc,  // (T,B,H)
                               const float* __restrict__ W, int ldw,
                               const float* __restrict__ addv, int add_per_b,
                               const float* __restrict__ dotv, int dot_per_b,
                               float* __restrict__ out) {      // (B*T), zeroed
    __shared__ float As[64][BK + 1];
    __shared__ float Bs[64][BK + 1];
    __shared__ float red[64];
    int r0 = blockIdx.x * 64;            // global row (b*T + t)
    int c0 = blockIdx.y * 64;
    int tid = threadIdx.x;
    int b  = r0 / T_;
    int t0 = r0 % T_;
    int tx = tid & 15, ty = tid >> 4;
    float acc[4][4] = {};
    for (int k0 = 0; k0 < H_; k0 += BK) {
        for (int l = tid; l < 64 * BK; l += 256) {
            int row = l / BK, k = l % BK;
            As[row][k] = enc[((size_t)(t0 + row) * B_ + b) * H_ + k0 + k];
            Bs[row][k] = W[(size_t)(c0 + row) * ldw + k0 + k];
        }
        __syncthreads();
        #pragma unroll
        for (int kk = 0; kk < BK; ++kk) {
            float a[4], bb[4];
            #pragma unroll
            for (int i = 0; i < 4; i++) a[i] = As[ty * 4 + i][kk];
            #pragma unroll
            for (int j = 0; j < 4; j++) bb[j] = Bs[tx * 4 + j][kk];
            #pragma unroll
            for (int i = 0; i < 4; i++)
                #pragma unroll
                for (int j = 0; j < 4; j++) acc[i][j] += a[i] * bb[j];
        }
        __syncthreads();
    }
    if (tid < 64) red[tid] = 0.f;
    __syncthreads();
    #pragma unroll
    for (int i = 0; i < 4; i++) {
        float rs = 0.f;
        #pragma unroll
        for (int j = 0; j < 4; j++) {
            int col = c0 + tx * 4 + j;
            float addt = add_per_b ? addv[b * H_ + col] : addv[col];
            float e = tanhf(acc[i][j] + addt);
            float d = dot_per_b ? dotv[b * H_ + col] : dotv[col];
            rs += d * e;
        }
        atomicAdd(&red[ty * 4 + i], rs);
    }
    __syncthreads();
    if (tid < 64) atomicAdd(&out[r0 + tid], red[tid]);
}

// ---------------- alpha = softmax over T per b ----------------
__global__ void softmax_t_k(const float* __restrict__ score, float* __restrict__ alpha) {
    __shared__ float red[T_];
    int b = blockIdx.x, t = threadIdx.x;
    float v = score[b * T_ + t];
    red[t] = v; __syncthreads();
    for (int s = 64; s > 0; s >>= 1) { if (t < s) red[t] = fmaxf(red[t], red[t + s]); __syncthreads(); }
    float m = red[0]; __syncthreads();
    float e = expf(v - m);
    red[t] = e; __syncthreads();
    for (int s = 64; s > 0; s >>= 1) { if (t < s) red[t] += red[t + s]; __syncthreads(); }
    alpha[b * T_ + t] = e / red[0];
}

// ---------------- ctx = alpha-weighted sum over enc ----------------
__global__ void ctx_k(const float* __restrict__ enc, const float* __restrict__ alpha,
                      float* __restrict__ ctx, float* __restrict__ xcat) {
    __shared__ float al[T_];
    int b = blockIdx.x;
    int h = blockIdx.y * 256 + threadIdx.x;
    if (threadIdx.x < T_) al[threadIdx.x] = alpha[b * T_ + threadIdx.x];
    __syncthreads();
    float s = 0.f;
    for (int t = 0; t < T_; ++t) s += al[t] * enc[((size_t)t * B_ + b) * H_ + h];
    ctx[b * H_ + h] = s;
    xcat[b * 1024 + 512 + h] = s;
}

// ---------------- GRU elementwise ----------------
__global__ void gru_k(const float* __restrict__ gi, const float* __restrict__ gh,
                      const float* __restrict__ hprev,
                      float* __restrict__ out, float* __restrict__ hnew,
                      float* __restrict__ xcat) {
    int b = blockIdx.x;
    int m = blockIdx.y * 256 + threadIdx.x;
    float ir = gi[b * 1536 + m],        hr = gh[b * 1536 + m];
    float iz = gi[b * 1536 + 512 + m],  hz = gh[b * 1536 + 512 + m];
    float in_ = gi[b * 1536 + 1024 + m], hn = gh[b * 1536 + 1024 + m];
    float r = 1.f / (1.f + expf(-(ir + hr)));
    float z = 1.f / (1.f + expf(-(iz + hz)));
    float n = tanhf(in_ + r * hn);
    float h = hprev[b * 512 + m];
    float hv = (1.f - z) * n + z * h;
    out[b * 512 + m] = hv;                 // gru_out
    out[B_ * 512 + b * 512 + m] = hv;      // new_hidden
    hnew[b * 512 + m] = hv;
    xcat[b * 1024 + m] = hv;
}

// ---------------- gen_score via bf16 MFMA, LDS-free, barrier-free --------
// gen[b][v] = bias[v] + sum_k xcat[b][k] * Wp[v][k]
// One wave owns a 64(b) x 16(v) tile across full K=1024.
// A-frag: A[m=lane&15][k=(lane>>4)*8+j]  (m89/m120-verified layout)
// B-frag: B[k][n=lane&15], k=(lane>>4)*8+j
// C/D   : col(n)=lane&15, row(m)=(lane>>4)*4+reg
__global__ __launch_bounds__(256) void proj_mfma_k(
        const float* __restrict__ xcat,   // (64,1024)
        const float* __restrict__ Wp,     // (V,1024)
        const float* __restrict__ bp,     // (V)
        float* __restrict__ gen) {        // (64,V)
    int lane = threadIdx.x & 63;
    int wave = threadIdx.x >> 6;
    int n0 = (blockIdx.x * 4 + wave) * 16;
    int col = lane & 15;
    int kq  = (lane >> 4) * 8;
    const float* wrow = Wp + (size_t)(n0 + col) * 1024 + kq;
    floatx4 acc[4] = {};
    for (int k0 = 0; k0 < 1024; k0 += 32) {
        const float4* wb = (const float4*)(wrow + k0);
        float4 b0 = wb[0], b1 = wb[1];
        bf16x8 fb;
        fb[0] = (__bf16)b0.x; fb[1] = (__bf16)b0.y; fb[2] = (__bf16)b0.z; fb[3] = (__bf16)b0.w;
        fb[4] = (__bf16)b1.x; fb[5] = (__bf16)b1.y; fb[6] = (__bf16)b1.z; fb[7] = (__bf16)b1.w;
        #pragma unroll
        for (int mi = 0; mi < 4; ++mi) {
            const float4* ar = (const float4*)(xcat + (size_t)(mi * 16 + col) * 1024 + k0 + kq);
            float4 a0 = ar[0], a1 = ar[1];
            bf16x8 fa;
            fa[0] = (__bf16)a0.x; fa[1] = (__bf16)a0.y; fa[2] = (__bf16)a0.z; fa[3] = (__bf16)a0.w;
            fa[4] = (__bf16)a1.x; fa[5] = (__bf16)a1.y; fa[6] = (__bf16)a1.z; fa[7] = (__bf16)a1.w;
            acc[mi] = __builtin_amdgcn_mfma_f32_16x16x32_bf16(fa, fb, acc[mi], 0, 0, 0);
        }
    }
    int rbase = (lane >> 4) * 4;
    float bias = bp[n0 + col];
    #pragma unroll
    for (int mi = 0; mi < 4; ++mi)
        #pragma unroll
        for (int r = 0; r < 4; ++r) {
            int b = mi * 16 + rbase + r;
            gen[(size_t)b * V_ + n0 + col] = acc[mi][r] + bias;
        }
}

// ---------------- raw stats: cmax, ex, total ----------------
__global__ void raw_stats_k(float* __restrict__ raw, float* __restrict__ cmax,
                            float* __restrict__ total) {
    __shared__ float red[T_];
    int b = blockIdx.x, t = threadIdx.x;
    float v = raw[b * T_ + t];
    red[t] = v; __syncthreads();
    for (int s = 64; s > 0; s >>= 1) { if (t < s) red[t] = fmaxf(red[t], red[t + s]); __syncthreads(); }
    float m = red[0]; __syncthreads();
    float e = expf(v - m);
    red[t] = e; __syncthreads();
    for (int s = 64; s > 0; s >>= 1) { if (t < s) red[t] += red[t + s]; __syncthreads(); }
    if (t == 0) { cmax[b] = m; total[b] = red[0]; }
    raw[b * T_ + t] = e;   // overwrite with exp
}

// ---------------- scatter ex into scat ----------------
__global__ void scatter_k(const float* __restrict__ ex, const int* __restrict__ u_input,
                          float* __restrict__ scat) {
    int b = blockIdx.x, t = threadIdx.x;
    int id = u_input[t * B_ + b];
    if (id != 0) {
        int j = (id == UNK_) ? (V_ + t) : id;
        atomicAdd(&scat[(size_t)b * VT_ + j], ex[b * T_ + t]);
    }
}

// ---------------- final: concat softmax + proba ----------------
__global__ void final_k(const float* __restrict__ gen, const float* __restrict__ scat,
                        const float* __restrict__ cmax, const float* __restrict__ total,
                        float* __restrict__ proba) {
    __shared__ float rmax[256], rsum[256], rgmax[256];
    __shared__ float sh[4];
    int b = blockIdx.x, tid = threadIdx.x;
    const float* sr = scat + (size_t)b * VT_;
    const float* gr = gen + (size_t)b * V_;
    float smax = 0.f, ssum = 0.f, gmax = -1e30f;
    for (int j = tid; j < VT_; j += 256) {
        float s = sr[j];
        smax = fmaxf(smax, s); ssum += s;
        if (j < V_) gmax = fmaxf(gmax, gr[j]);
    }
    rmax[tid] = smax; rsum[tid] = ssum; rgmax[tid] = gmax; __syncthreads();
    for (int s = 128; s > 0; s >>= 1) {
        if (tid < s) {
            rmax[tid] = fmaxf(rmax[tid], rmax[tid + s]);
            rsum[tid] += rsum[tid + s];
            rgmax[tid] = fmaxf(rgmax[tid], rgmax[tid + s]);
        }
        __syncthreads();
    }
    float cm = cmax[b], tot = total[b];
    if (tid == 0) {
        float umax = cm + logf(EPS_ * tot + (1.f - EPS_) * rmax[0]);
        sh[0] = fmaxf(rgmax[0], umax);
        sh[3] = rsum[0];
    }
    __syncthreads();
    float M = sh[0];
    float zg = 0.f;
    for (int j = tid; j < V_; j += 256) zg += expf(gr[j] - M);
    rsum[tid] = zg; __syncthreads();
    for (int s = 128; s > 0; s >>= 1) { if (tid < s) rsum[tid] += rsum[tid + s]; __syncthreads(); }
    if (tid == 0) {
        float coef = expf(cm - M);
        float Z = rsum[0] + coef * (EPS_ * tot * (float)VT_ + (1.f - EPS_) * sh[3]);
        sh[1] = 1.f / Z;
        sh[2] = coef;
    }
    __syncthreads();
    float invZ = sh[1], coef = sh[2];
    float* pr = proba + (size_t)b * VT_;
    for (int j = tid; j < VT_; j += 256) {
        float c = coef * (EPS_ * tot + (1.f - EPS_) * sr[j]) * invZ;
        float p = c + ((j < V_) ? expf(gr[j] - M) * invZ : 0.f);
        pr[j] = p;
    }
}

extern "C" void kernel_launch(void* const* d_in, const int* in_sizes, int n_in,
                              void* d_out, int out_size, void* d_ws, size_t ws_size,
                              hipStream_t stream) {
    const float* u_enc   = (const float*)d_in[0];
    const int*   z_tm1   = (const int*)d_in[1];
    const float* last_h  = (const float*)d_in[2];
    const int*   u_input = (const int*)d_in[3];
    const float* emb     = (const float*)d_in[4];
    const float* attn_W  = (const float*)d_in[5];
    const float* attn_b  = (const float*)d_in[6];
    const float* attn_v  = (const float*)d_in[7];
    const float* gru_Wih = (const float*)d_in[8];
    const float* gru_Whh = (const float*)d_in[9];
    const float* gru_bih = (const float*)d_in[10];
    const float* gru_bhh = (const float*)d_in[11];
    const float* proj_W  = (const float*)d_in[12];
    const float* proj_b  = (const float*)d_in[13];
    const float* copy1_W = (const float*)d_in[14];
    const float* copy1_b = (const float*)d_in[15];
    float* out = (float*)d_out;

    float* ws    = (float*)d_ws;
    // atomic targets contiguous at the front, zeroed with one kernel
    float* score = ws;                          // B*T
    float* rawb  = score + B_ * T_;             // B*T
    float* scat  = rawb + B_ * T_;              // B*VT
    float* Wh    = scat + (size_t)B_ * VT_;     // B*H
    float* gh    = Wh + B_ * H_;                // B*1536
    float* alpha = gh + B_ * 1536;              // B*T
    float* ctx   = alpha + B_ * T_;             // B*H
    float* gi    = ctx + B_ * H_;               // B*1536
    float* hnew  = gi + B_ * 1536;              // B*H
    float* xcat  = hnew + B_ * H_;              // B*1024
    float* gen   = xcat + B_ * 1024;            // B*V
    float* cmaxb = gen + (size_t)B_ * V_;       // B
    float* totalb= cmaxb + B_;                  // B

    int nzero = B_ * T_ * 2 + B_ * VT_;
    zero_k<<<(nzero + 255) / 256, 256, 0, stream>>>(ws, nzero);

    // Wh = attn_W[:, :H] @ h + attn_b ; gh = gru_Whh @ h + gru_bhh
    matvec_k<<<B_ * H_ / 4, 256, 0, stream>>>(attn_W, 2 * H_, last_h, attn_b, Wh, H_, H_);
    matvec_k<<<B_ * 1536 / 4, 256, 0, stream>>>(gru_Whh, H_, last_h, gru_bhh, gh, 1536, H_);

    dim3 g2(T_ * B_ / 64, H_ / 64);
    // attn scores: score[b,t] = sum_hh attn_v[hh]*tanh(Wh[b,hh] + enc.attn_W2)
    enc_gemm_dot_k<<<g2, 256, 0, stream>>>(u_enc, attn_W + H_, 2 * H_, Wh, 1, attn_v, 0, score);
    softmax_t_k<<<B_, T_, 0, stream>>>(score, alpha);
    ctx_k<<<dim3(B_, 2), 256, 0, stream>>>(u_enc, alpha, ctx, xcat);

    gi_matvec_k<<<B_ * 1536 / 4, 256, 0, stream>>>(gru_Wih, emb, z_tm1, ctx, gru_bih, gi);
    gru_k<<<dim3(B_, 2), 256, 0, stream>>>(gi, gh, last_h, out, hnew, xcat);

    proj_mfma_k<<<V_ / 64, 256, 0, stream>>>(xcat, proj_W, proj_b, gen);

    // copy raw: raw[b,t] = sum_i hnew[b,i]*tanh(copy1_b[i] + enc.copy1_W)
    enc_gemm_dot_k<<<g2, 256, 0, stream>>>(u_enc, copy1_W, H_, copy1_b, 0, hnew, 1, rawb);

    raw_stats_k<<<B_, T_, 0, stream>>>(rawb, cmaxb, totalb);
    scatter_k<<<B_, T_, 0, stream>>>(rawb, u_input, scat);
    final_k<<<B_, 256, 0, stream>>>(gen, scat, cmaxb, totalb, out + 2 * B_ * H_);
}

// Round 3
// 579.493 us; speedup vs baseline: 1.5791x; 1.2094x over previous
//
#include <hip/hip_runtime.h>
#include <math.h>

#define T_ 128
#define B_ 64
#define H_ 512
#define E_ 256
#define V_ 32000
#define VT_ (V_ + T_)   // 32128
#define UNK_ 2
#define EPS_ 1e-10f

typedef __attribute__((ext_vector_type(8))) __bf16 bf16x8;
typedef __attribute__((ext_vector_type(4))) float floatx4;

// ---------------- zero helper (atomic targets) ----------------
__global__ void zero_k(float* __restrict__ p, int n) {
    int i = blockIdx.x * 256 + threadIdx.x;
    if (i < n) p[i] = 0.f;
}

// ---------------- fp32 -> bf16 converters ----------------
__global__ void cvt_flat_k(const float* __restrict__ src, __bf16* __restrict__ dst, int n) {
    int i = (blockIdx.x * 256 + threadIdx.x) * 8;
    if (i >= n) return;
    float4 a = *(const float4*)(src + i);
    float4 b = *(const float4*)(src + i + 4);
    bf16x8 o;
    o[0] = (__bf16)a.x; o[1] = (__bf16)a.y; o[2] = (__bf16)a.z; o[3] = (__bf16)a.w;
    o[4] = (__bf16)b.x; o[5] = (__bf16)b.y; o[6] = (__bf16)b.z; o[7] = (__bf16)b.w;
    *(bf16x8*)(dst + i) = o;
}

// strided 512x512 slice -> packed bf16
__global__ void cvt_w_k(const float* __restrict__ src, int ld, int off,
                        __bf16* __restrict__ dst) {
    int r = blockIdx.x;
    int c = threadIdx.x * 2;
    float2 v = *(const float2*)(src + (size_t)r * ld + off + c);
    dst[r * H_ + c]     = (__bf16)v.x;
    dst[r * H_ + c + 1] = (__bf16)v.y;
}

// ---------------- generic batched matvec ----------------------
__global__ void matvec_k(const float* __restrict__ W, int ldw,
                         const float* __restrict__ x,
                         const float* __restrict__ bias,
                         float* __restrict__ out, int M, int K) {
    int wid  = blockIdx.x * 4 + (threadIdx.x >> 6);
    int lane = threadIdx.x & 63;
    int b = wid / M, m = wid % M;
    if (b >= B_) return;
    const float* wr = W + (size_t)m * ldw;
    const float* xr = x + (size_t)b * K;
    float s = 0.f;
    for (int k = lane; k < K; k += 64) s += wr[k] * xr[k];
    #pragma unroll
    for (int off = 32; off > 0; off >>= 1) s += __shfl_down(s, off);
    if (lane == 0) out[b * M + m] = s + bias[m];
}

// gi matvec with gathered x = [emb[z[b]] (E), ctx[b] (H)]
__global__ void gi_matvec_k(const float* __restrict__ Wih,  // (1536, 768)
                            const float* __restrict__ emb,
                            const int* __restrict__ z,
                            const float* __restrict__ ctx,
                            const float* __restrict__ bih,
                            float* __restrict__ gi) {
    const int M = 1536, K = 768;
    int wid  = blockIdx.x * 4 + (threadIdx.x >> 6);
    int lane = threadIdx.x & 63;
    int b = wid / M, m = wid % M;
    if (b >= B_) return;
    const float* wr = Wih + (size_t)m * K;
    const float* er = emb + (size_t)z[b] * E_;
    const float* cr = ctx + (size_t)b * H_;
    float s = 0.f;
    for (int k = lane; k < K; k += 64) {
        float xv = (k < E_) ? er[k] : cr[k - E_];
        s += wr[k] * xv;
    }
    #pragma unroll
    for (int off = 32; off > 0; off >>= 1) s += __shfl_down(s, off);
    if (lane == 0) gi[b * M + m] = s + bih[m];
}

// ------- enc GEMM via bf16 MFMA with fused tanh+dot epilogue -------
// out[row=b*T+t] += sum_{col in wave's 16} dotv[col]*tanh(C[row,col]+addv[col])
// Wave: 64 rows x 16 cols, full K=512. All fragments direct from global (bf16).
__global__ __launch_bounds__(256) void enc_mfma_dot_k(
        const __bf16* __restrict__ enc_bf,  // (T,B,H)
        const __bf16* __restrict__ Wb,      // (512,512) packed
        const float* __restrict__ addv, int add_per_b,
        const float* __restrict__ dotv, int dot_per_b,
        float* __restrict__ out) {          // (B*T), zeroed
    int lane = threadIdx.x & 63;
    int wave = threadIdx.x >> 6;
    int r0 = blockIdx.x * 64;           // global row (b*T + t)
    int b  = r0 / T_;
    int t0 = r0 % T_;
    int n0 = blockIdx.y * 64 + wave * 16;
    int coln = lane & 15;
    int kq   = (lane >> 4) * 8;
    const __bf16* wrow = Wb + (size_t)(n0 + coln) * H_ + kq;
    floatx4 acc[4] = {};
    #pragma unroll 4
    for (int k0 = 0; k0 < H_; k0 += 32) {
        bf16x8 fb = *(const bf16x8*)(wrow + k0);
        #pragma unroll
        for (int mi = 0; mi < 4; ++mi) {
            const __bf16* arow = enc_bf +
                ((size_t)(t0 + mi * 16 + coln) * B_ + b) * H_ + k0 + kq;
            bf16x8 fa = *(const bf16x8*)arow;
            acc[mi] = __builtin_amdgcn_mfma_f32_16x16x32_bf16(fa, fb, acc[mi], 0, 0, 0);
        }
    }
    int col = n0 + coln;
    float addt = add_per_b ? addv[b * H_ + col] : addv[col];
    float dt   = dot_per_b ? dotv[b * H_ + col] : dotv[col];
    int rbase = (lane >> 4) * 4;
    #pragma unroll
    for (int mi = 0; mi < 4; ++mi)
        #pragma unroll
        for (int r = 0; r < 4; ++r) {
            // fast tanh: (e^{2x}-1)/(e^{2x}+1)
            float x = acc[mi][r] + addt;
            float t = __expf(2.f * x);
            float v = dt * ((t - 1.f) / (t + 1.f));
            v += __shfl_xor(v, 1);
            v += __shfl_xor(v, 2);
            v += __shfl_xor(v, 4);
            v += __shfl_xor(v, 8);
            if (coln == 0) atomicAdd(&out[r0 + mi * 16 + rbase + r], v);
        }
}

// ---------------- alpha = softmax over T per b ----------------
__global__ void softmax_t_k(const float* __restrict__ score, float* __restrict__ alpha) {
    __shared__ float red[T_];
    int b = blockIdx.x, t = threadIdx.x;
    float v = score[b * T_ + t];
    red[t] = v; __syncthreads();
    for (int s = 64; s > 0; s >>= 1) { if (t < s) red[t] = fmaxf(red[t], red[t + s]); __syncthreads(); }
    float m = red[0]; __syncthreads();
    float e = expf(v - m);
    red[t] = e; __syncthreads();
    for (int s = 64; s > 0; s >>= 1) { if (t < s) red[t] += red[t + s]; __syncthreads(); }
    alpha[b * T_ + t] = e / red[0];
}

// ---------------- ctx = alpha-weighted sum over enc ----------------
__global__ void ctx_k(const float* __restrict__ enc, const float* __restrict__ alpha,
                      float* __restrict__ ctx, float* __restrict__ xcat) {
    __shared__ float al[T_];
    int b = blockIdx.x;
    int h = blockIdx.y * 256 + threadIdx.x;
    if (threadIdx.x < T_) al[threadIdx.x] = alpha[b * T_ + threadIdx.x];
    __syncthreads();
    float s = 0.f;
    for (int t = 0; t < T_; ++t) s += al[t] * enc[((size_t)t * B_ + b) * H_ + h];
    ctx[b * H_ + h] = s;
    xcat[b * 1024 + 512 + h] = s;
}

// ---------------- GRU elementwise ----------------
__global__ void gru_k(const float* __restrict__ gi, const float* __restrict__ gh,
                      const float* __restrict__ hprev,
                      float* __restrict__ out, float* __restrict__ hnew,
                      float* __restrict__ xcat) {
    int b = blockIdx.x;
    int m = blockIdx.y * 256 + threadIdx.x;
    float ir = gi[b * 1536 + m],        hr = gh[b * 1536 + m];
    float iz = gi[b * 1536 + 512 + m],  hz = gh[b * 1536 + 512 + m];
    float in_ = gi[b * 1536 + 1024 + m], hn = gh[b * 1536 + 1024 + m];
    float r = 1.f / (1.f + expf(-(ir + hr)));
    float z = 1.f / (1.f + expf(-(iz + hz)));
    float n = tanhf(in_ + r * hn);
    float h = hprev[b * 512 + m];
    float hv = (1.f - z) * n + z * h;
    out[b * 512 + m] = hv;                 // gru_out
    out[B_ * 512 + b * 512 + m] = hv;      // new_hidden
    hnew[b * 512 + m] = hv;
    xcat[b * 1024 + m] = hv;
}

// ---------------- gen_score via bf16 MFMA, 4-way K-split --------
// gen (zeroed) += partial; kh==0 slice adds bias.
__global__ __launch_bounds__(256) void proj_mfma_k(
        const float* __restrict__ xcat,   // (64,1024)
        const float* __restrict__ Wp,     // (V,1024)
        const float* __restrict__ bp,     // (V)
        float* __restrict__ gen) {        // (64,V), zeroed
    int lane = threadIdx.x & 63;
    int wave = threadIdx.x >> 6;
    int n0 = (blockIdx.x * 4 + wave) * 16;
    int kh = blockIdx.y;                  // 0..3, covers k in [kh*256, kh*256+256)
    int col = lane & 15;
    int kq  = (lane >> 4) * 8;
    const float* wrow = Wp + (size_t)(n0 + col) * 1024 + kh * 256 + kq;
    const float* abase = xcat + kh * 256 + kq;
    floatx4 acc[4] = {};
    for (int k0 = 0; k0 < 256; k0 += 32) {
        const float4* wb = (const float4*)(wrow + k0);
        float4 b0 = wb[0], b1 = wb[1];
        bf16x8 fb;
        fb[0] = (__bf16)b0.x; fb[1] = (__bf16)b0.y; fb[2] = (__bf16)b0.z; fb[3] = (__bf16)b0.w;
        fb[4] = (__bf16)b1.x; fb[5] = (__bf16)b1.y; fb[6] = (__bf16)b1.z; fb[7] = (__bf16)b1.w;
        #pragma unroll
        for (int mi = 0; mi < 4; ++mi) {
            const float4* ar = (const float4*)(abase + (size_t)(mi * 16 + col) * 1024 + k0);
            float4 a0 = ar[0], a1 = ar[1];
            bf16x8 fa;
            fa[0] = (__bf16)a0.x; fa[1] = (__bf16)a0.y; fa[2] = (__bf16)a0.z; fa[3] = (__bf16)a0.w;
            fa[4] = (__bf16)a1.x; fa[5] = (__bf16)a1.y; fa[6] = (__bf16)a1.z; fa[7] = (__bf16)a1.w;
            acc[mi] = __builtin_amdgcn_mfma_f32_16x16x32_bf16(fa, fb, acc[mi], 0, 0, 0);
        }
    }
    int rbase = (lane >> 4) * 4;
    float bias = (kh == 0) ? bp[n0 + col] : 0.f;
    #pragma unroll
    for (int mi = 0; mi < 4; ++mi)
        #pragma unroll
        for (int r = 0; r < 4; ++r) {
            int b = mi * 16 + rbase + r;
            atomicAdd(&gen[(size_t)b * V_ + n0 + col], acc[mi][r] + bias);
        }
}

// ---------------- raw stats: cmax, ex, total ----------------
__global__ void raw_stats_k(float* __restrict__ raw, float* __restrict__ cmax,
                            float* __restrict__ total) {
    __shared__ float red[T_];
    int b = blockIdx.x, t = threadIdx.x;
    float v = raw[b * T_ + t];
    red[t] = v; __syncthreads();
    for (int s = 64; s > 0; s >>= 1) { if (t < s) red[t] = fmaxf(red[t], red[t + s]); __syncthreads(); }
    float m = red[0]; __syncthreads();
    float e = expf(v - m);
    red[t] = e; __syncthreads();
    for (int s = 64; s > 0; s >>= 1) { if (t < s) red[t] += red[t + s]; __syncthreads(); }
    if (t == 0) { cmax[b] = m; total[b] = red[0]; }
    raw[b * T_ + t] = e;   // overwrite with exp
}

// ---------------- scatter ex into scat ----------------
__global__ void scatter_k(const float* __restrict__ ex, const int* __restrict__ u_input,
                          float* __restrict__ scat) {
    int b = blockIdx.x, t = threadIdx.x;
    int id = u_input[t * B_ + b];
    if (id != 0) {
        int j = (id == UNK_) ? (V_ + t) : id;
        atomicAdd(&scat[(size_t)b * VT_ + j], ex[b * T_ + t]);
    }
}

// ---------------- final: concat softmax + proba ----------------
__global__ void final_k(const float* __restrict__ gen, const float* __restrict__ scat,
                        const float* __restrict__ cmax, const float* __restrict__ total,
                        float* __restrict__ proba) {
    __shared__ float rmax[256], rsum[256], rgmax[256];
    __shared__ float sh[4];
    int b = blockIdx.x, tid = threadIdx.x;
    const float* sr = scat + (size_t)b * VT_;
    const float* gr = gen + (size_t)b * V_;
    float smax = 0.f, ssum = 0.f, gmax = -1e30f;
    for (int j = tid; j < VT_; j += 256) {
        float s = sr[j];
        smax = fmaxf(smax, s); ssum += s;
        if (j < V_) gmax = fmaxf(gmax, gr[j]);
    }
    rmax[tid] = smax; rsum[tid] = ssum; rgmax[tid] = gmax; __syncthreads();
    for (int s = 128; s > 0; s >>= 1) {
        if (tid < s) {
            rmax[tid] = fmaxf(rmax[tid], rmax[tid + s]);
            rsum[tid] += rsum[tid + s];
            rgmax[tid] = fmaxf(rgmax[tid], rgmax[tid + s]);
        }
        __syncthreads();
    }
    float cm = cmax[b], tot = total[b];
    if (tid == 0) {
        float umax = cm + logf(EPS_ * tot + (1.f - EPS_) * rmax[0]);
        sh[0] = fmaxf(rgmax[0], umax);
        sh[3] = rsum[0];
    }
    __syncthreads();
    float M = sh[0];
    float zg = 0.f;
    for (int j = tid; j < V_; j += 256) zg += expf(gr[j] - M);
    rsum[tid] = zg; __syncthreads();
    for (int s = 128; s > 0; s >>= 1) { if (tid < s) rsum[tid] += rsum[tid + s]; __syncthreads(); }
    if (tid == 0) {
        float coef = expf(cm - M);
        float Z = rsum[0] + coef * (EPS_ * tot * (float)VT_ + (1.f - EPS_) * sh[3]);
        sh[1] = 1.f / Z;
        sh[2] = coef;
    }
    __syncthreads();
    float invZ = sh[1], coef = sh[2];
    float* pr = proba + (size_t)b * VT_;
    for (int j = tid; j < VT_; j += 256) {
        float c = coef * (EPS_ * tot + (1.f - EPS_) * sr[j]) * invZ;
        float p = c + ((j < V_) ? expf(gr[j] - M) * invZ : 0.f);
        pr[j] = p;
    }
}

extern "C" void kernel_launch(void* const* d_in, const int* in_sizes, int n_in,
                              void* d_out, int out_size, void* d_ws, size_t ws_size,
                              hipStream_t stream) {
    const float* u_enc   = (const float*)d_in[0];
    const int*   z_tm1   = (const int*)d_in[1];
    const float* last_h  = (const float*)d_in[2];
    const int*   u_input = (const int*)d_in[3];
    const float* emb     = (const float*)d_in[4];
    const float* attn_W  = (const float*)d_in[5];
    const float* attn_b  = (const float*)d_in[6];
    const float* attn_v  = (const float*)d_in[7];
    const float* gru_Wih = (const float*)d_in[8];
    const float* gru_Whh = (const float*)d_in[9];
    const float* gru_bih = (const float*)d_in[10];
    const float* gru_bhh = (const float*)d_in[11];
    const float* proj_W  = (const float*)d_in[12];
    const float* proj_b  = (const float*)d_in[13];
    const float* copy1_W = (const float*)d_in[14];
    const float* copy1_b = (const float*)d_in[15];
    float* out = (float*)d_out;

    float* ws    = (float*)d_ws;
    // atomic targets contiguous at the front, zeroed with one kernel
    float* score = ws;                          // B*T
    float* rawb  = score + B_ * T_;             // B*T
    float* scat  = rawb + B_ * T_;              // B*VT
    float* gen   = scat + (size_t)B_ * VT_;     // B*V   (atomic, zeroed)
    float* Wh    = gen + (size_t)B_ * V_;       // B*H
    float* gh    = Wh + B_ * H_;                // B*1536
    float* alpha = gh + B_ * 1536;              // B*T
    float* ctx   = alpha + B_ * T_;             // B*H
    float* gi    = ctx + B_ * H_;               // B*1536
    float* hnew  = gi + B_ * 1536;              // B*H
    float* xcat  = hnew + B_ * H_;              // B*1024
    float* cmaxb = xcat + B_ * 1024;            // B
    float* totalb= cmaxb + B_;                  // B
    __bf16* enc_bf  = (__bf16*)(totalb + B_);   // T*B*H bf16
    __bf16* Wb_attn = enc_bf + (size_t)T_ * B_ * H_;   // 512*512
    __bf16* Wb_copy = Wb_attn + H_ * H_;               // 512*512

    int nzero = B_ * T_ * 2 + B_ * VT_ + B_ * V_;
    zero_k<<<(nzero + 255) / 256, 256, 0, stream>>>(ws, nzero);

    // bf16 pre-conversions
    cvt_flat_k<<<(T_ * B_ * H_ / 8 + 255) / 256, 256, 0, stream>>>(u_enc, enc_bf, T_ * B_ * H_);
    cvt_w_k<<<H_, 256, 0, stream>>>(attn_W, 2 * H_, H_, Wb_attn);
    cvt_w_k<<<H_, 256, 0, stream>>>(copy1_W, H_, 0, Wb_copy);

    // Wh = attn_W[:, :H] @ h + attn_b ; gh = gru_Whh @ h + gru_bhh
    matvec_k<<<B_ * H_ / 4, 256, 0, stream>>>(attn_W, 2 * H_, last_h, attn_b, Wh, H_, H_);
    matvec_k<<<B_ * 1536 / 4, 256, 0, stream>>>(gru_Whh, H_, last_h, gru_bhh, gh, 1536, H_);

    dim3 g2(T_ * B_ / 64, H_ / 64);
    enc_mfma_dot_k<<<g2, 256, 0, stream>>>(enc_bf, Wb_attn, Wh, 1, attn_v, 0, score);
    softmax_t_k<<<B_, T_, 0, stream>>>(score, alpha);
    ctx_k<<<dim3(B_, 2), 256, 0, stream>>>(u_enc, alpha, ctx, xcat);

    gi_matvec_k<<<B_ * 1536 / 4, 256, 0, stream>>>(gru_Wih, emb, z_tm1, ctx, gru_bih, gi);
    gru_k<<<dim3(B_, 2), 256, 0, stream>>>(gi, gh, last_h, out, hnew, xcat);

    proj_mfma_k<<<dim3(V_ / 64, 4), 256, 0, stream>>>(xcat, proj_W, proj_b, gen);

    enc_mfma_dot_k<<<g2, 256, 0, stream>>>(enc_bf, Wb_copy, copy1_b, 0, hnew, 1, rawb);

    raw_stats_k<<<B_, T_, 0, stream>>>(rawb, cmaxb, totalb);
    scatter_k<<<B_, T_, 0, stream>>>(rawb, u_input, scat);
    final_k<<<B_, 256, 0, stream>>>(gen, scat, cmaxb, totalb, out + 2 * B_ * H_);
}

// Round 4
// 501.305 us; speedup vs baseline: 1.8254x; 1.1560x over previous
//
#include <hip/hip_runtime.h>
#include <math.h>

#define T_ 128
#define B_ 64
#define H_ 512
#define E_ 256
#define V_ 32000
#define VT_ (V_ + T_)   // 32128
#define UNK_ 2
#define EPS_ 1e-10f
#define NS_ 16          // gen_stats chunks per row (V/NS = 2000)

typedef __attribute__((ext_vector_type(8))) __bf16 bf16x8;
typedef __attribute__((ext_vector_type(4))) float floatx4;

// ---------------- zero helper (atomic targets) ----------------
__global__ void zero_k(float* __restrict__ p, int n) {
    int i = blockIdx.x * 256 + threadIdx.x;
    if (i < n) p[i] = 0.f;
}

// ---------------- fp32 -> bf16 converters ----------------
__global__ void cvt_flat_k(const float* __restrict__ src, __bf16* __restrict__ dst, int n) {
    int i = (blockIdx.x * 256 + threadIdx.x) * 8;
    if (i >= n) return;
    float4 a = *(const float4*)(src + i);
    float4 b = *(const float4*)(src + i + 4);
    bf16x8 o;
    o[0] = (__bf16)a.x; o[1] = (__bf16)a.y; o[2] = (__bf16)a.z; o[3] = (__bf16)a.w;
    o[4] = (__bf16)b.x; o[5] = (__bf16)b.y; o[6] = (__bf16)b.z; o[7] = (__bf16)b.w;
    *(bf16x8*)(dst + i) = o;
}

// strided 512x512 slice -> packed bf16
__global__ void cvt_w_k(const float* __restrict__ src, int ld, int off,
                        __bf16* __restrict__ dst) {
    int r = blockIdx.x;
    int c = threadIdx.x * 2;
    float2 v = *(const float2*)(src + (size_t)r * ld + off + c);
    dst[r * H_ + c]     = (__bf16)v.x;
    dst[r * H_ + c + 1] = (__bf16)v.y;
}

// ---------------- generic batched matvec ----------------------
__global__ void matvec_k(const float* __restrict__ W, int ldw,
                         const float* __restrict__ x,
                         const float* __restrict__ bias,
                         float* __restrict__ out, int M, int K) {
    int wid  = blockIdx.x * 4 + (threadIdx.x >> 6);
    int lane = threadIdx.x & 63;
    int b = wid / M, m = wid % M;
    if (b >= B_) return;
    const float* wr = W + (size_t)m * ldw;
    const float* xr = x + (size_t)b * K;
    float s = 0.f;
    for (int k = lane; k < K; k += 64) s += wr[k] * xr[k];
    #pragma unroll
    for (int off = 32; off > 0; off >>= 1) s += __shfl_down(s, off);
    if (lane == 0) out[b * M + m] = s + bias[m];
}

// gi matvec with gathered x = [emb[z[b]] (E), ctx[b] (H)]
__global__ void gi_matvec_k(const float* __restrict__ Wih,  // (1536, 768)
                            const float* __restrict__ emb,
                            const int* __restrict__ z,
                            const float* __restrict__ ctx,
                            const float* __restrict__ bih,
                            float* __restrict__ gi) {
    const int M = 1536, K = 768;
    int wid  = blockIdx.x * 4 + (threadIdx.x >> 6);
    int lane = threadIdx.x & 63;
    int b = wid / M, m = wid % M;
    if (b >= B_) return;
    const float* wr = Wih + (size_t)m * K;
    const float* er = emb + (size_t)z[b] * E_;
    const float* cr = ctx + (size_t)b * H_;
    float s = 0.f;
    for (int k = lane; k < K; k += 64) {
        float xv = (k < E_) ? er[k] : cr[k - E_];
        s += wr[k] * xv;
    }
    #pragma unroll
    for (int off = 32; off > 0; off >>= 1) s += __shfl_down(s, off);
    if (lane == 0) gi[b * M + m] = s + bih[m];
}

// ------- enc GEMM via bf16 MFMA with fused tanh+dot epilogue -------
__global__ __launch_bounds__(256) void enc_mfma_dot_k(
        const __bf16* __restrict__ enc_bf,  // (T,B,H)
        const __bf16* __restrict__ Wb,      // (512,512) packed
        const float* __restrict__ addv, int add_per_b,
        const float* __restrict__ dotv, int dot_per_b,
        float* __restrict__ out) {          // (B*T), zeroed
    int lane = threadIdx.x & 63;
    int wave = threadIdx.x >> 6;
    int r0 = blockIdx.x * 64;           // global row (b*T + t)
    int b  = r0 / T_;
    int t0 = r0 % T_;
    int n0 = blockIdx.y * 64 + wave * 16;
    int coln = lane & 15;
    int kq   = (lane >> 4) * 8;
    const __bf16* wrow = Wb + (size_t)(n0 + coln) * H_ + kq;
    floatx4 acc[4] = {};
    #pragma unroll 4
    for (int k0 = 0; k0 < H_; k0 += 32) {
        bf16x8 fb = *(const bf16x8*)(wrow + k0);
        #pragma unroll
        for (int mi = 0; mi < 4; ++mi) {
            const __bf16* arow = enc_bf +
                ((size_t)(t0 + mi * 16 + coln) * B_ + b) * H_ + k0 + kq;
            bf16x8 fa = *(const bf16x8*)arow;
            acc[mi] = __builtin_amdgcn_mfma_f32_16x16x32_bf16(fa, fb, acc[mi], 0, 0, 0);
        }
    }
    int col = n0 + coln;
    float addt = add_per_b ? addv[b * H_ + col] : addv[col];
    float dt   = dot_per_b ? dotv[b * H_ + col] : dotv[col];
    int rbase = (lane >> 4) * 4;
    #pragma unroll
    for (int mi = 0; mi < 4; ++mi)
        #pragma unroll
        for (int r = 0; r < 4; ++r) {
            float x = acc[mi][r] + addt;
            float t = __expf(2.f * x);
            float v = dt * ((t - 1.f) / (t + 1.f));
            v += __shfl_xor(v, 1);
            v += __shfl_xor(v, 2);
            v += __shfl_xor(v, 4);
            v += __shfl_xor(v, 8);
            if (coln == 0) atomicAdd(&out[r0 + mi * 16 + rbase + r], v);
        }
}

// ---------------- alpha = softmax over T per b ----------------
__global__ void softmax_t_k(const float* __restrict__ score, float* __restrict__ alpha) {
    __shared__ float red[T_];
    int b = blockIdx.x, t = threadIdx.x;
    float v = score[b * T_ + t];
    red[t] = v; __syncthreads();
    for (int s = 64; s > 0; s >>= 1) { if (t < s) red[t] = fmaxf(red[t], red[t + s]); __syncthreads(); }
    float m = red[0]; __syncthreads();
    float e = expf(v - m);
    red[t] = e; __syncthreads();
    for (int s = 64; s > 0; s >>= 1) { if (t < s) red[t] += red[t + s]; __syncthreads(); }
    alpha[b * T_ + t] = e / red[0];
}

// ---------------- ctx = alpha-weighted sum over enc ----------------
__global__ void ctx_k(const float* __restrict__ enc, const float* __restrict__ alpha,
                      float* __restrict__ ctx, float* __restrict__ xcat) {
    __shared__ float al[T_];
    int b = blockIdx.x;
    int h = blockIdx.y * 256 + threadIdx.x;
    if (threadIdx.x < T_) al[threadIdx.x] = alpha[b * T_ + threadIdx.x];
    __syncthreads();
    float s = 0.f;
    for (int t = 0; t < T_; ++t) s += al[t] * enc[((size_t)t * B_ + b) * H_ + h];
    ctx[b * H_ + h] = s;
    xcat[b * 1024 + 512 + h] = s;
}

// ---------------- GRU elementwise ----------------
__global__ void gru_k(const float* __restrict__ gi, const float* __restrict__ gh,
                      const float* __restrict__ hprev,
                      float* __restrict__ out, float* __restrict__ hnew,
                      float* __restrict__ xcat) {
    int b = blockIdx.x;
    int m = blockIdx.y * 256 + threadIdx.x;
    float ir = gi[b * 1536 + m],        hr = gh[b * 1536 + m];
    float iz = gi[b * 1536 + 512 + m],  hz = gh[b * 1536 + 512 + m];
    float in_ = gi[b * 1536 + 1024 + m], hn = gh[b * 1536 + 1024 + m];
    float r = 1.f / (1.f + expf(-(ir + hr)));
    float z = 1.f / (1.f + expf(-(iz + hz)));
    float n = tanhf(in_ + r * hn);
    float h = hprev[b * 512 + m];
    float hv = (1.f - z) * n + z * h;
    out[b * 512 + m] = hv;                 // gru_out
    out[B_ * 512 + b * 512 + m] = hv;      // new_hidden
    hnew[b * 512 + m] = hv;
    xcat[b * 1024 + m] = hv;
}

// ---------------- gen_score via bf16 MFMA, 4-way K-split --------
__global__ __launch_bounds__(256) void proj_mfma_k(
        const float* __restrict__ xcat,   // (64,1024)
        const float* __restrict__ Wp,     // (V,1024)
        const float* __restrict__ bp,     // (V)
        float* __restrict__ gen) {        // (64,V), zeroed
    int lane = threadIdx.x & 63;
    int wave = threadIdx.x >> 6;
    int n0 = (blockIdx.x * 4 + wave) * 16;
    int kh = blockIdx.y;                  // 0..3
    int col = lane & 15;
    int kq  = (lane >> 4) * 8;
    const float* wrow = Wp + (size_t)(n0 + col) * 1024 + kh * 256 + kq;
    const float* abase = xcat + kh * 256 + kq;
    floatx4 acc[4] = {};
    for (int k0 = 0; k0 < 256; k0 += 32) {
        const float4* wb = (const float4*)(wrow + k0);
        float4 b0 = wb[0], b1 = wb[1];
        bf16x8 fb;
        fb[0] = (__bf16)b0.x; fb[1] = (__bf16)b0.y; fb[2] = (__bf16)b0.z; fb[3] = (__bf16)b0.w;
        fb[4] = (__bf16)b1.x; fb[5] = (__bf16)b1.y; fb[6] = (__bf16)b1.z; fb[7] = (__bf16)b1.w;
        #pragma unroll
        for (int mi = 0; mi < 4; ++mi) {
            const float4* ar = (const float4*)(abase + (size_t)(mi * 16 + col) * 1024 + k0);
            float4 a0 = ar[0], a1 = ar[1];
            bf16x8 fa;
            fa[0] = (__bf16)a0.x; fa[1] = (__bf16)a0.y; fa[2] = (__bf16)a0.z; fa[3] = (__bf16)a0.w;
            fa[4] = (__bf16)a1.x; fa[5] = (__bf16)a1.y; fa[6] = (__bf16)a1.z; fa[7] = (__bf16)a1.w;
            acc[mi] = __builtin_amdgcn_mfma_f32_16x16x32_bf16(fa, fb, acc[mi], 0, 0, 0);
        }
    }
    int rbase = (lane >> 4) * 4;
    float bias = (kh == 0) ? bp[n0 + col] : 0.f;
    #pragma unroll
    for (int mi = 0; mi < 4; ++mi)
        #pragma unroll
        for (int r = 0; r < 4; ++r) {
            int b = mi * 16 + rbase + r;
            atomicAdd(&gen[(size_t)b * V_ + n0 + col], acc[mi][r] + bias);
        }
}

// ---------------- raw stats: cmax, ex, total ----------------
__global__ void raw_stats_k(float* __restrict__ raw, float* __restrict__ cmax,
                            float* __restrict__ total) {
    __shared__ float red[T_];
    int b = blockIdx.x, t = threadIdx.x;
    float v = raw[b * T_ + t];
    red[t] = v; __syncthreads();
    for (int s = 64; s > 0; s >>= 1) { if (t < s) red[t] = fmaxf(red[t], red[t + s]); __syncthreads(); }
    float m = red[0]; __syncthreads();
    float e = expf(v - m);
    red[t] = e; __syncthreads();
    for (int s = 64; s > 0; s >>= 1) { if (t < s) red[t] += red[t + s]; __syncthreads(); }
    if (t == 0) { cmax[b] = m; total[b] = red[0]; }
    raw[b * T_ + t] = e;   // overwrite with exp
}

// ---------------- zero only touched scat positions ----------------
__global__ void zero_scat_k(const int* __restrict__ u_input, float* __restrict__ scat) {
    int b = blockIdx.x, t = threadIdx.x;
    int id = u_input[t * B_ + b];
    if (id != 0) {
        int j = (id == UNK_) ? (V_ + t) : id;
        scat[(size_t)b * VT_ + j] = 0.f;
    }
}

// ---------------- scatter ex into scat ----------------
__global__ void scatter_k(const float* __restrict__ ex, const int* __restrict__ u_input,
                          float* __restrict__ scat) {
    int b = blockIdx.x, t = threadIdx.x;
    int id = u_input[t * B_ + b];
    if (id != 0) {
        int j = (id == UNK_) ? (V_ + t) : id;
        atomicAdd(&scat[(size_t)b * VT_ + j], ex[b * T_ + t]);
    }
}

// ---------------- gen per-chunk online softmax partials ----------------
__global__ __launch_bounds__(256) void gen_stats_k(const float* __restrict__ gen,
                                                   float* __restrict__ mpart,
                                                   float* __restrict__ lpart) {
    int b = blockIdx.x, s = blockIdx.y, tid = threadIdx.x;
    const int C = V_ / NS_;   // 2000
    const float* gr = gen + (size_t)b * V_ + s * C;
    __shared__ float red[256];
    float m = -1e30f;
    for (int j = tid; j < C; j += 256) m = fmaxf(m, gr[j]);
    red[tid] = m; __syncthreads();
    for (int st = 128; st > 0; st >>= 1) { if (tid < st) red[tid] = fmaxf(red[tid], red[tid + st]); __syncthreads(); }
    m = red[0]; __syncthreads();
    float l = 0.f;
    for (int j = tid; j < C; j += 256) l += __expf(gr[j] - m);
    red[tid] = l; __syncthreads();
    for (int st = 128; st > 0; st >>= 1) { if (tid < st) red[tid] += red[tid + st]; __syncthreads(); }
    if (tid == 0) { mpart[b * NS_ + s] = m; lpart[b * NS_ + s] = red[0]; }
}

// ---------------- combine partials -> per-row params ----------------
__global__ void combine_k(const float* __restrict__ mpart, const float* __restrict__ lpart,
                          const float* __restrict__ scat, const float* __restrict__ ex,
                          const int* __restrict__ u_input,
                          const float* __restrict__ cmax, const float* __restrict__ total,
                          float* __restrict__ params) {
    int b = blockIdx.x, t = threadIdx.x;   // 128 threads
    __shared__ float sm[T_], ss[T_];
    int id = u_input[t * B_ + b];
    float sv = 0.f, ev = 0.f;
    if (id != 0) {
        int j = (id == UNK_) ? (V_ + t) : id;
        sv = scat[(size_t)b * VT_ + j];
        ev = ex[b * T_ + t];
    }
    sm[t] = sv; ss[t] = ev; __syncthreads();
    for (int st = 64; st > 0; st >>= 1) {
        if (t < st) { sm[t] = fmaxf(sm[t], sm[t + st]); ss[t] += ss[t + st]; }
        __syncthreads();
    }
    if (t == 0) {
        float Mg = -1e30f;
        for (int s = 0; s < NS_; s++) Mg = fmaxf(Mg, mpart[b * NS_ + s]);
        float cm = cmax[b], tot = total[b];
        float smax = sm[0], ssum = ss[0];
        float umax = cm + logf(EPS_ * tot + (1.f - EPS_) * smax);
        float M = fmaxf(Mg, umax);
        float Zg = 0.f;
        for (int s = 0; s < NS_; s++) Zg += lpart[b * NS_ + s] * __expf(mpart[b * NS_ + s] - M);
        float coef = __expf(cm - M);
        float Z = Zg + coef * (EPS_ * tot * (float)VT_ + (1.f - EPS_) * ssum);
        float invZ = 1.f / Z;
        params[b * 4 + 0] = M;
        params[b * 4 + 1] = invZ;
        params[b * 4 + 2] = coef * EPS_ * tot * invZ;      // addc
        params[b * 4 + 3] = coef * (1.f - EPS_) * invZ;    // scoef
    }
}

// ---------------- streamed proba write (no scat read) ----------------
__global__ __launch_bounds__(256) void write_k(const float* __restrict__ gen,
                                               const float* __restrict__ params,
                                               float* __restrict__ proba) {
    int b = blockIdx.y;
    int i4 = blockIdx.x * 256 + threadIdx.x;   // float4 index
    if (i4 >= VT_ / 4) return;
    float M = params[b * 4], invZ = params[b * 4 + 1], addc = params[b * 4 + 2];
    int j = i4 * 4;
    float4 p;
    if (j < V_) {
        float4 g = *(const float4*)(gen + (size_t)b * V_ + j);
        p.x = addc + __expf(g.x - M) * invZ;
        p.y = addc + __expf(g.y - M) * invZ;
        p.z = addc + __expf(g.z - M) * invZ;
        p.w = addc + __expf(g.w - M) * invZ;
    } else {
        p.x = p.y = p.z = p.w = addc;
    }
    *(float4*)(proba + (size_t)b * VT_ + j) = p;
}

// ---------------- overwrite scattered positions with full value ----------
__global__ void fix_k(const float* __restrict__ gen, const float* __restrict__ scat,
                      const int* __restrict__ u_input, const float* __restrict__ params,
                      float* __restrict__ proba) {
    int b = blockIdx.x, t = threadIdx.x;
    int id = u_input[t * B_ + b];
    if (id == 0) return;
    int j = (id == UNK_) ? (V_ + t) : id;
    float M = params[b * 4], invZ = params[b * 4 + 1];
    float addc = params[b * 4 + 2], scoef = params[b * 4 + 3];
    float p = addc + scoef * scat[(size_t)b * VT_ + j];
    if (j < V_) p += __expf(gen[(size_t)b * V_ + j] - M) * invZ;
    proba[(size_t)b * VT_ + j] = p;
}

extern "C" void kernel_launch(void* const* d_in, const int* in_sizes, int n_in,
                              void* d_out, int out_size, void* d_ws, size_t ws_size,
                              hipStream_t stream) {
    const float* u_enc   = (const float*)d_in[0];
    const int*   z_tm1   = (const int*)d_in[1];
    const float* last_h  = (const float*)d_in[2];
    const int*   u_input = (const int*)d_in[3];
    const float* emb     = (const float*)d_in[4];
    const float* attn_W  = (const float*)d_in[5];
    const float* attn_b  = (const float*)d_in[6];
    const float* attn_v  = (const float*)d_in[7];
    const float* gru_Wih = (const float*)d_in[8];
    const float* gru_Whh = (const float*)d_in[9];
    const float* gru_bih = (const float*)d_in[10];
    const float* gru_bhh = (const float*)d_in[11];
    const float* proj_W  = (const float*)d_in[12];
    const float* proj_b  = (const float*)d_in[13];
    const float* copy1_W = (const float*)d_in[14];
    const float* copy1_b = (const float*)d_in[15];
    float* out = (float*)d_out;

    float* ws    = (float*)d_ws;
    // atomic targets needing zero-init contiguous at the front
    float* score = ws;                          // B*T
    float* rawb  = score + B_ * T_;             // B*T
    float* gen   = rawb + B_ * T_;              // B*V   (atomic, zeroed)
    float* scat  = gen + (size_t)B_ * V_;       // B*VT  (sparse-zeroed)
    float* Wh    = scat + (size_t)B_ * VT_;     // B*H
    float* gh    = Wh + B_ * H_;                // B*1536
    float* alpha = gh + B_ * 1536;              // B*T
    float* ctx   = alpha + B_ * T_;             // B*H
    float* gi    = ctx + B_ * H_;               // B*1536
    float* hnew  = gi + B_ * 1536;              // B*H
    float* xcat  = hnew + B_ * H_;              // B*1024
    float* cmaxb = xcat + B_ * 1024;            // B
    float* totalb= cmaxb + B_;                  // B
    float* mpart = totalb + B_;                 // B*NS
    float* lpart = mpart + B_ * NS_;            // B*NS
    float* params= lpart + B_ * NS_;            // B*4
    __bf16* enc_bf  = (__bf16*)(params + B_ * 4);      // T*B*H bf16
    __bf16* Wb_attn = enc_bf + (size_t)T_ * B_ * H_;   // 512*512
    __bf16* Wb_copy = Wb_attn + H_ * H_;               // 512*512

    int nzero = B_ * T_ * 2 + B_ * V_;
    zero_k<<<(nzero + 255) / 256, 256, 0, stream>>>(ws, nzero);

    // bf16 pre-conversions
    cvt_flat_k<<<(T_ * B_ * H_ / 8 + 255) / 256, 256, 0, stream>>>(u_enc, enc_bf, T_ * B_ * H_);
    cvt_w_k<<<H_, 256, 0, stream>>>(attn_W, 2 * H_, H_, Wb_attn);
    cvt_w_k<<<H_, 256, 0, stream>>>(copy1_W, H_, 0, Wb_copy);

    matvec_k<<<B_ * H_ / 4, 256, 0, stream>>>(attn_W, 2 * H_, last_h, attn_b, Wh, H_, H_);
    matvec_k<<<B_ * 1536 / 4, 256, 0, stream>>>(gru_Whh, H_, last_h, gru_bhh, gh, 1536, H_);

    dim3 g2(T_ * B_ / 64, H_ / 64);
    enc_mfma_dot_k<<<g2, 256, 0, stream>>>(enc_bf, Wb_attn, Wh, 1, attn_v, 0, score);
    softmax_t_k<<<B_, T_, 0, stream>>>(score, alpha);
    ctx_k<<<dim3(B_, 2), 256, 0, stream>>>(u_enc, alpha, ctx, xcat);

    gi_matvec_k<<<B_ * 1536 / 4, 256, 0, stream>>>(gru_Wih, emb, z_tm1, ctx, gru_bih, gi);
    gru_k<<<dim3(B_, 2), 256, 0, stream>>>(gi, gh, last_h, out, hnew, xcat);

    proj_mfma_k<<<dim3(V_ / 64, 4), 256, 0, stream>>>(xcat, proj_W, proj_b, gen);

    enc_mfma_dot_k<<<g2, 256, 0, stream>>>(enc_bf, Wb_copy, copy1_b, 0, hnew, 1, rawb);

    raw_stats_k<<<B_, T_, 0, stream>>>(rawb, cmaxb, totalb);
    zero_scat_k<<<B_, T_, 0, stream>>>(u_input, scat);
    scatter_k<<<B_, T_, 0, stream>>>(rawb, u_input, scat);

    gen_stats_k<<<dim3(B_, NS_), 256, 0, stream>>>(gen, mpart, lpart);
    combine_k<<<B_, T_, 0, stream>>>(mpart, lpart, scat, rawb, u_input, cmaxb, totalb, params);
    float* proba = out + 2 * B_ * H_;
    write_k<<<dim3((VT_ / 4 + 255) / 256, B_), 256, 0, stream>>>(gen, params, proba);
    fix_k<<<B_, T_, 0, stream>>>(gen, scat, u_input, params, proba);
}

// Round 5
// 433.439 us; speedup vs baseline: 2.1112x; 1.1566x over previous
//
#include <hip/hip_runtime.h>
#include <math.h>

#define T_ 128
#define B_ 64
#define H_ 512
#define E_ 256
#define V_ 32000
#define VT_ (V_ + T_)   // 32128
#define UNK_ 2
#define EPS_ 1e-10f
#define NS_ 16          // gen_stats chunks per row (V/NS = 2000)

typedef __attribute__((ext_vector_type(8))) __bf16 bf16x8;
typedef __attribute__((ext_vector_type(4))) float floatx4;

// ---------------- zero helper (atomic targets) ----------------
__global__ void zero_k(float* __restrict__ p, int n) {
    int i = blockIdx.x * 256 + threadIdx.x;
    if (i < n) p[i] = 0.f;
}

// ---------------- fp32 -> bf16 converters ----------------
__global__ void cvt_flat_k(const float* __restrict__ src, __bf16* __restrict__ dst, int n) {
    int i = (blockIdx.x * 256 + threadIdx.x) * 8;
    if (i >= n) return;
    float4 a = *(const float4*)(src + i);
    float4 b = *(const float4*)(src + i + 4);
    bf16x8 o;
    o[0] = (__bf16)a.x; o[1] = (__bf16)a.y; o[2] = (__bf16)a.z; o[3] = (__bf16)a.w;
    o[4] = (__bf16)b.x; o[5] = (__bf16)b.y; o[6] = (__bf16)b.z; o[7] = (__bf16)b.w;
    *(bf16x8*)(dst + i) = o;
}

// strided 512x512 slice -> packed bf16
__global__ void cvt_w_k(const float* __restrict__ src, int ld, int off,
                        __bf16* __restrict__ dst) {
    int r = blockIdx.x;
    int c = threadIdx.x * 2;
    float2 v = *(const float2*)(src + (size_t)r * ld + off + c);
    dst[r * H_ + c]     = (__bf16)v.x;
    dst[r * H_ + c + 1] = (__bf16)v.y;
}

// ---------------- generic batched matvec (float4) ----------------------
__global__ void matvec_k(const float* __restrict__ W, int ldw,
                         const float* __restrict__ x,
                         const float* __restrict__ bias,
                         float* __restrict__ out, int M, int K) {
    int wid  = blockIdx.x * 4 + (threadIdx.x >> 6);
    int lane = threadIdx.x & 63;
    int b = wid / M, m = wid % M;
    if (b >= B_) return;
    const float4* wr = (const float4*)(W + (size_t)m * ldw);
    const float4* xr = (const float4*)(x + (size_t)b * K);
    float s = 0.f;
    for (int k = lane; k < K / 4; k += 64) {
        float4 w = wr[k], xv = xr[k];
        s += w.x * xv.x + w.y * xv.y + w.z * xv.z + w.w * xv.w;
    }
    #pragma unroll
    for (int off = 32; off > 0; off >>= 1) s += __shfl_down(s, off);
    if (lane == 0) out[b * M + m] = s + bias[m];
}

// gi matvec with gathered x = [emb[z[b]] (E), ctx[b] (H)]
__global__ void gi_matvec_k(const float* __restrict__ Wih,  // (1536, 768)
                            const float* __restrict__ emb,
                            const int* __restrict__ z,
                            const float* __restrict__ ctx,
                            const float* __restrict__ bih,
                            float* __restrict__ gi) {
    const int M = 1536, K = 768;
    int wid  = blockIdx.x * 4 + (threadIdx.x >> 6);
    int lane = threadIdx.x & 63;
    int b = wid / M, m = wid % M;
    if (b >= B_) return;
    const float4* wr = (const float4*)(Wih + (size_t)m * K);
    const float4* er = (const float4*)(emb + (size_t)z[b] * E_);
    const float4* cr = (const float4*)(ctx + (size_t)b * H_);
    float s = 0.f;
    for (int k = lane; k < K / 4; k += 64) {
        float4 xv = (k < E_ / 4) ? er[k] : cr[k - E_ / 4];
        float4 w = wr[k];
        s += w.x * xv.x + w.y * xv.y + w.z * xv.z + w.w * xv.w;
    }
    #pragma unroll
    for (int off = 32; off > 0; off >>= 1) s += __shfl_down(s, off);
    if (lane == 0) gi[b * M + m] = s + bih[m];
}

// ------- enc GEMM via bf16 MFMA with fused tanh+dot epilogue -------
__global__ __launch_bounds__(256) void enc_mfma_dot_k(
        const __bf16* __restrict__ enc_bf,  // (T,B,H)
        const __bf16* __restrict__ Wb,      // (512,512) packed
        const float* __restrict__ addv, int add_per_b,
        const float* __restrict__ dotv, int dot_per_b,
        float* __restrict__ out) {          // (B*T), zeroed
    int lane = threadIdx.x & 63;
    int wave = threadIdx.x >> 6;
    int r0 = blockIdx.x * 64;           // global row (b*T + t)
    int b  = r0 / T_;
    int t0 = r0 % T_;
    int n0 = blockIdx.y * 64 + wave * 16;
    int coln = lane & 15;
    int kq   = (lane >> 4) * 8;
    const __bf16* wrow = Wb + (size_t)(n0 + coln) * H_ + kq;
    floatx4 acc[4] = {};
    #pragma unroll 4
    for (int k0 = 0; k0 < H_; k0 += 32) {
        bf16x8 fb = *(const bf16x8*)(wrow + k0);
        #pragma unroll
        for (int mi = 0; mi < 4; ++mi) {
            const __bf16* arow = enc_bf +
                ((size_t)(t0 + mi * 16 + coln) * B_ + b) * H_ + k0 + kq;
            bf16x8 fa = *(const bf16x8*)arow;
            acc[mi] = __builtin_amdgcn_mfma_f32_16x16x32_bf16(fa, fb, acc[mi], 0, 0, 0);
        }
    }
    int col = n0 + coln;
    float addt = add_per_b ? addv[b * H_ + col] : addv[col];
    float dt   = dot_per_b ? dotv[b * H_ + col] : dotv[col];
    int rbase = (lane >> 4) * 4;
    #pragma unroll
    for (int mi = 0; mi < 4; ++mi)
        #pragma unroll
        for (int r = 0; r < 4; ++r) {
            float x = acc[mi][r] + addt;
            float t = __expf(2.f * x);
            float v = dt * ((t - 1.f) / (t + 1.f));
            v += __shfl_xor(v, 1);
            v += __shfl_xor(v, 2);
            v += __shfl_xor(v, 4);
            v += __shfl_xor(v, 8);
            if (coln == 0) atomicAdd(&out[r0 + mi * 16 + rbase + r], v);
        }
}

// ---------------- alpha = softmax over T per b ----------------
__global__ void softmax_t_k(const float* __restrict__ score, float* __restrict__ alpha) {
    __shared__ float red[T_];
    int b = blockIdx.x, t = threadIdx.x;
    float v = score[b * T_ + t];
    red[t] = v; __syncthreads();
    for (int s = 64; s > 0; s >>= 1) { if (t < s) red[t] = fmaxf(red[t], red[t + s]); __syncthreads(); }
    float m = red[0]; __syncthreads();
    float e = expf(v - m);
    red[t] = e; __syncthreads();
    for (int s = 64; s > 0; s >>= 1) { if (t < s) red[t] += red[t + s]; __syncthreads(); }
    alpha[b * T_ + t] = e / red[0];
}

// ---------------- ctx = alpha-weighted sum over enc ----------------
__global__ void ctx_k(const float* __restrict__ enc, const float* __restrict__ alpha,
                      float* __restrict__ ctx, __bf16* __restrict__ xcat_bf) {
    __shared__ float al[T_];
    int b = blockIdx.x;
    int h = blockIdx.y * 256 + threadIdx.x;
    if (threadIdx.x < T_) al[threadIdx.x] = alpha[b * T_ + threadIdx.x];
    __syncthreads();
    float s = 0.f;
    for (int t = 0; t < T_; ++t) s += al[t] * enc[((size_t)t * B_ + b) * H_ + h];
    ctx[b * H_ + h] = s;
    xcat_bf[b * 1024 + 512 + h] = (__bf16)s;
}

// ---------------- GRU elementwise ----------------
__global__ void gru_k(const float* __restrict__ gi, const float* __restrict__ gh,
                      const float* __restrict__ hprev,
                      float* __restrict__ out, float* __restrict__ hnew,
                      __bf16* __restrict__ xcat_bf) {
    int b = blockIdx.x;
    int m = blockIdx.y * 256 + threadIdx.x;
    float ir = gi[b * 1536 + m],        hr = gh[b * 1536 + m];
    float iz = gi[b * 1536 + 512 + m],  hz = gh[b * 1536 + 512 + m];
    float in_ = gi[b * 1536 + 1024 + m], hn = gh[b * 1536 + 1024 + m];
    float r = 1.f / (1.f + expf(-(ir + hr)));
    float z = 1.f / (1.f + expf(-(iz + hz)));
    float n = tanhf(in_ + r * hn);
    float h = hprev[b * 512 + m];
    float hv = (1.f - z) * n + z * h;
    out[b * 512 + m] = hv;                 // gru_out
    out[B_ * 512 + b * 512 + m] = hv;      // new_hidden
    hnew[b * 512 + m] = hv;
    xcat_bf[b * 1024 + m] = (__bf16)hv;
}

// ---------------- gen_score via bf16 MFMA, full-K, direct store --------
__global__ __launch_bounds__(256) void proj_mfma_k(
        const __bf16* __restrict__ xcat_bf, // (64,1024) bf16
        const float* __restrict__ Wp,       // (V,1024) fp32
        const float* __restrict__ bp,       // (V)
        float* __restrict__ gen) {          // (64,V)
    int lane = threadIdx.x & 63;
    int wave = threadIdx.x >> 6;
    int n0 = (blockIdx.x * 4 + wave) * 16;
    int col = lane & 15;
    int kq  = (lane >> 4) * 8;
    const float* wrow = Wp + (size_t)(n0 + col) * 1024 + kq;
    const __bf16* abase = xcat_bf + kq;
    floatx4 acc[4] = {};
    #pragma unroll 4
    for (int k0 = 0; k0 < 1024; k0 += 32) {
        const float4* wb = (const float4*)(wrow + k0);
        float4 b0 = wb[0], b1 = wb[1];
        bf16x8 fb;
        fb[0] = (__bf16)b0.x; fb[1] = (__bf16)b0.y; fb[2] = (__bf16)b0.z; fb[3] = (__bf16)b0.w;
        fb[4] = (__bf16)b1.x; fb[5] = (__bf16)b1.y; fb[6] = (__bf16)b1.z; fb[7] = (__bf16)b1.w;
        #pragma unroll
        for (int mi = 0; mi < 4; ++mi) {
            bf16x8 fa = *(const bf16x8*)(abase + (size_t)(mi * 16 + col) * 1024 + k0);
            acc[mi] = __builtin_amdgcn_mfma_f32_16x16x32_bf16(fa, fb, acc[mi], 0, 0, 0);
        }
    }
    int rbase = (lane >> 4) * 4;
    float bias = bp[n0 + col];
    #pragma unroll
    for (int mi = 0; mi < 4; ++mi)
        #pragma unroll
        for (int r = 0; r < 4; ++r) {
            int b = mi * 16 + rbase + r;
            gen[(size_t)b * V_ + n0 + col] = acc[mi][r] + bias;
        }
}

// ---------------- raw stats: cmax, ex, total ----------------
__global__ void raw_stats_k(float* __restrict__ raw, float* __restrict__ cmax,
                            float* __restrict__ total) {
    __shared__ float red[T_];
    int b = blockIdx.x, t = threadIdx.x;
    float v = raw[b * T_ + t];
    red[t] = v; __syncthreads();
    for (int s = 64; s > 0; s >>= 1) { if (t < s) red[t] = fmaxf(red[t], red[t + s]); __syncthreads(); }
    float m = red[0]; __syncthreads();
    float e = expf(v - m);
    red[t] = e; __syncthreads();
    for (int s = 64; s > 0; s >>= 1) { if (t < s) red[t] += red[t + s]; __syncthreads(); }
    if (t == 0) { cmax[b] = m; total[b] = red[0]; }
    raw[b * T_ + t] = e;   // overwrite with exp
}

// ---------------- zero only touched scat positions ----------------
__global__ void zero_scat_k(const int* __restrict__ u_input, float* __restrict__ scat) {
    int b = blockIdx.x, t = threadIdx.x;
    int id = u_input[t * B_ + b];
    if (id != 0) {
        int j = (id == UNK_) ? (V_ + t) : id;
        scat[(size_t)b * VT_ + j] = 0.f;
    }
}

// ---------------- scatter ex into scat ----------------
__global__ void scatter_k(const float* __restrict__ ex, const int* __restrict__ u_input,
                          float* __restrict__ scat) {
    int b = blockIdx.x, t = threadIdx.x;
    int id = u_input[t * B_ + b];
    if (id != 0) {
        int j = (id == UNK_) ? (V_ + t) : id;
        atomicAdd(&scat[(size_t)b * VT_ + j], ex[b * T_ + t]);
    }
}

// ---------------- gen per-chunk online softmax partials ----------------
__global__ __launch_bounds__(256) void gen_stats_k(const float* __restrict__ gen,
                                                   float* __restrict__ mpart,
                                                   float* __restrict__ lpart) {
    int b = blockIdx.x, s = blockIdx.y, tid = threadIdx.x;
    const int C = V_ / NS_;   // 2000
    const float* gr = gen + (size_t)b * V_ + s * C;
    __shared__ float red[256];
    float m = -1e30f;
    for (int j = tid; j < C; j += 256) m = fmaxf(m, gr[j]);
    red[tid] = m; __syncthreads();
    for (int st = 128; st > 0; st >>= 1) { if (tid < st) red[tid] = fmaxf(red[tid], red[tid + st]); __syncthreads(); }
    m = red[0]; __syncthreads();
    float l = 0.f;
    for (int j = tid; j < C; j += 256) l += __expf(gr[j] - m);
    red[tid] = l; __syncthreads();
    for (int st = 128; st > 0; st >>= 1) { if (tid < st) red[tid] += red[tid + st]; __syncthreads(); }
    if (tid == 0) { mpart[b * NS_ + s] = m; lpart[b * NS_ + s] = red[0]; }
}

// ---------------- combine partials -> per-row params ----------------
__global__ void combine_k(const float* __restrict__ mpart, const float* __restrict__ lpart,
                          const float* __restrict__ scat, const float* __restrict__ ex,
                          const int* __restrict__ u_input,
                          const float* __restrict__ cmax, const float* __restrict__ total,
                          float* __restrict__ params) {
    int b = blockIdx.x, t = threadIdx.x;   // 128 threads
    __shared__ float sm[T_], ss[T_];
    int id = u_input[t * B_ + b];
    float sv = 0.f, ev = 0.f;
    if (id != 0) {
        int j = (id == UNK_) ? (V_ + t) : id;
        sv = scat[(size_t)b * VT_ + j];
        ev = ex[b * T_ + t];
    }
    sm[t] = sv; ss[t] = ev; __syncthreads();
    for (int st = 64; st > 0; st >>= 1) {
        if (t < st) { sm[t] = fmaxf(sm[t], sm[t + st]); ss[t] += ss[t + st]; }
        __syncthreads();
    }
    if (t == 0) {
        float Mg = -1e30f;
        for (int s = 0; s < NS_; s++) Mg = fmaxf(Mg, mpart[b * NS_ + s]);
        float cm = cmax[b], tot = total[b];
        float smax = sm[0], ssum = ss[0];
        float umax = cm + logf(EPS_ * tot + (1.f - EPS_) * smax);
        float M = fmaxf(Mg, umax);
        float Zg = 0.f;
        for (int s = 0; s < NS_; s++) Zg += lpart[b * NS_ + s] * __expf(mpart[b * NS_ + s] - M);
        float coef = __expf(cm - M);
        float Z = Zg + coef * (EPS_ * tot * (float)VT_ + (1.f - EPS_) * ssum);
        float invZ = 1.f / Z;
        params[b * 4 + 0] = M;
        params[b * 4 + 1] = invZ;
        params[b * 4 + 2] = coef * EPS_ * tot * invZ;      // addc
        params[b * 4 + 3] = coef * (1.f - EPS_) * invZ;    // scoef
    }
}

// ---------------- streamed proba write (no scat read) ----------------
__global__ __launch_bounds__(256) void write_k(const float* __restrict__ gen,
                                               const float* __restrict__ params,
                                               float* __restrict__ proba) {
    int b = blockIdx.y;
    int i4 = blockIdx.x * 256 + threadIdx.x;   // float4 index
    if (i4 >= VT_ / 4) return;
    float M = params[b * 4], invZ = params[b * 4 + 1], addc = params[b * 4 + 2];
    int j = i4 * 4;
    float4 p;
    if (j < V_) {
        float4 g = *(const float4*)(gen + (size_t)b * V_ + j);
        p.x = addc + __expf(g.x - M) * invZ;
        p.y = addc + __expf(g.y - M) * invZ;
        p.z = addc + __expf(g.z - M) * invZ;
        p.w = addc + __expf(g.w - M) * invZ;
    } else {
        p.x = p.y = p.z = p.w = addc;
    }
    *(float4*)(proba + (size_t)b * VT_ + j) = p;
}

// ---------------- overwrite scattered positions with full value ----------
__global__ void fix_k(const float* __restrict__ gen, const float* __restrict__ scat,
                      const int* __restrict__ u_input, const float* __restrict__ params,
                      float* __restrict__ proba) {
    int b = blockIdx.x, t = threadIdx.x;
    int id = u_input[t * B_ + b];
    if (id == 0) return;
    int j = (id == UNK_) ? (V_ + t) : id;
    float M = params[b * 4], invZ = params[b * 4 + 1];
    float addc = params[b * 4 + 2], scoef = params[b * 4 + 3];
    float p = addc + scoef * scat[(size_t)b * VT_ + j];
    if (j < V_) p += __expf(gen[(size_t)b * V_ + j] - M) * invZ;
    proba[(size_t)b * VT_ + j] = p;
}

extern "C" void kernel_launch(void* const* d_in, const int* in_sizes, int n_in,
                              void* d_out, int out_size, void* d_ws, size_t ws_size,
                              hipStream_t stream) {
    const float* u_enc   = (const float*)d_in[0];
    const int*   z_tm1   = (const int*)d_in[1];
    const float* last_h  = (const float*)d_in[2];
    const int*   u_input = (const int*)d_in[3];
    const float* emb     = (const float*)d_in[4];
    const float* attn_W  = (const float*)d_in[5];
    const float* attn_b  = (const float*)d_in[6];
    const float* attn_v  = (const float*)d_in[7];
    const float* gru_Wih = (const float*)d_in[8];
    const float* gru_Whh = (const float*)d_in[9];
    const float* gru_bih = (const float*)d_in[10];
    const float* gru_bhh = (const float*)d_in[11];
    const float* proj_W  = (const float*)d_in[12];
    const float* proj_b  = (const float*)d_in[13];
    const float* copy1_W = (const float*)d_in[14];
    const float* copy1_b = (const float*)d_in[15];
    float* out = (float*)d_out;

    float* ws    = (float*)d_ws;
    // atomic targets needing zero-init contiguous at the front
    float* score = ws;                          // B*T  (zeroed)
    float* rawb  = score + B_ * T_;             // B*T  (zeroed)
    float* gen   = rawb + B_ * T_;              // B*V  (direct store now)
    float* scat  = gen + (size_t)B_ * V_;       // B*VT (sparse-zeroed)
    float* Wh    = scat + (size_t)B_ * VT_;     // B*H
    float* gh    = Wh + B_ * H_;                // B*1536
    float* alpha = gh + B_ * 1536;              // B*T
    float* ctx   = alpha + B_ * T_;             // B*H
    float* gi    = ctx + B_ * H_;               // B*1536
    float* hnew  = gi + B_ * 1536;              // B*H
    float* cmaxb = hnew + B_ * H_;              // B
    float* totalb= cmaxb + B_;                  // B
    float* mpart = totalb + B_;                 // B*NS
    float* lpart = mpart + B_ * NS_;            // B*NS
    float* params= lpart + B_ * NS_;            // B*4
    __bf16* xcat_bf = (__bf16*)(params + B_ * 4);      // 64*1024 bf16
    __bf16* enc_bf  = xcat_bf + B_ * 1024;             // T*B*H bf16
    __bf16* Wb_attn = enc_bf + (size_t)T_ * B_ * H_;   // 512*512
    __bf16* Wb_copy = Wb_attn + H_ * H_;               // 512*512

    int nzero = B_ * T_ * 2;
    zero_k<<<(nzero + 255) / 256, 256, 0, stream>>>(ws, nzero);

    // bf16 pre-conversions
    cvt_flat_k<<<(T_ * B_ * H_ / 8 + 255) / 256, 256, 0, stream>>>(u_enc, enc_bf, T_ * B_ * H_);
    cvt_w_k<<<H_, 256, 0, stream>>>(attn_W, 2 * H_, H_, Wb_attn);
    cvt_w_k<<<H_, 256, 0, stream>>>(copy1_W, H_, 0, Wb_copy);

    matvec_k<<<B_ * H_ / 4, 256, 0, stream>>>(attn_W, 2 * H_, last_h, attn_b, Wh, H_, H_);
    matvec_k<<<B_ * 1536 / 4, 256, 0, stream>>>(gru_Whh, H_, last_h, gru_bhh, gh, 1536, H_);

    dim3 g2(T_ * B_ / 64, H_ / 64);
    enc_mfma_dot_k<<<g2, 256, 0, stream>>>(enc_bf, Wb_attn, Wh, 1, attn_v, 0, score);
    softmax_t_k<<<B_, T_, 0, stream>>>(score, alpha);
    ctx_k<<<dim3(B_, 2), 256, 0, stream>>>(u_enc, alpha, ctx, xcat_bf);

    gi_matvec_k<<<B_ * 1536 / 4, 256, 0, stream>>>(gru_Wih, emb, z_tm1, ctx, gru_bih, gi);
    gru_k<<<dim3(B_, 2), 256, 0, stream>>>(gi, gh, last_h, out, hnew, xcat_bf);

    proj_mfma_k<<<V_ / 64, 256, 0, stream>>>(xcat_bf, proj_W, proj_b, gen);

    enc_mfma_dot_k<<<g2, 256, 0, stream>>>(enc_bf, Wb_copy, copy1_b, 0, hnew, 1, rawb);

    raw_stats_k<<<B_, T_, 0, stream>>>(rawb, cmaxb, totalb);
    zero_scat_k<<<B_, T_, 0, stream>>>(u_input, scat);
    scatter_k<<<B_, T_, 0, stream>>>(rawb, u_input, scat);

    gen_stats_k<<<dim3(B_, NS_), 256, 0, stream>>>(gen, mpart, lpart);
    combine_k<<<B_, T_, 0, stream>>>(mpart, lpart, scat, rawb, u_input, cmaxb, totalb, params);
    float* proba = out + 2 * B_ * H_;
    write_k<<<dim3((VT_ / 4 + 255) / 256, B_), 256, 0, stream>>>(gen, params, proba);
    fix_k<<<B_, T_, 0, stream>>>(gen, scat, u_input, params, proba);
}